// Round 15
// baseline (115.831 us; speedup 1.0000x reference)
//
#include <hip/hip_runtime.h>
#include <hip/hip_bf16.h>

#define IW    4096
#define OW    4096
#define PC    64
#define BATCH 1024
#define SB    4            // batches per slice; slice = 4096 rows x 4 x bf16 = 32 KB LDS
#define NSLICE (BATCH / SB)   // 256
#define OQ    4               // output quarters -> grid 1024

__device__ __forceinline__ float sigmoidf_(float x) {
    return 1.0f / (1.0f + __expf(-x));
}

__device__ __forceinline__ unsigned short f2bfbits(float f) {
    union { __hip_bfloat16 h; unsigned short u; } cv;
    cv.h = __float2bfloat16(f);   // RNE
    return cv.u;
}

// K1: x [BATCH][IW] f32 -> xS slice-major: xS[slice][IW][SB] bf16.
// Each thread's 4-batch quad (s*4) aligns exactly with one SB=4 slice row.
__global__ __launch_bounds__(256) void k_transpose_cast(
        const float* __restrict__ x, unsigned short* __restrict__ xS) {
    __shared__ float tile[64][65];          // [c_local][b_local], +1 pad
    const int c0 = blockIdx.x * 64;         // input-width tile
    const int b0 = blockIdx.y * 64;         // batch tile
    const int t  = threadIdx.x;
    const int r  = t >> 4;                  // 0..15
    const int s  = t & 15;                  // 0..15
    #pragma unroll
    for (int it = 0; it < 4; ++it) {
        const int row = r + 16 * it;        // batch row in tile
        const float4 v = *reinterpret_cast<const float4*>(
            x + (size_t)(b0 + row) * IW + c0 + s * 4);
        tile[s * 4 + 0][row] = v.x;
        tile[s * 4 + 1][row] = v.y;
        tile[s * 4 + 2][row] = v.z;
        tile[s * 4 + 3][row] = v.w;
    }
    __syncthreads();
    const int b4    = b0 + s * 4;           // first batch of this thread's quad
    const int slice = b4 >> 2;              // SB=4: quad == slice row
    unsigned short* dst = xS + (size_t)slice * IW * SB;
    #pragma unroll
    for (int it = 0; it < 4; ++it) {
        const int c = r + 16 * it;          // c_local
        ushort4 o;
        o.x = f2bfbits(tile[c][s * 4 + 0]);
        o.y = f2bfbits(tile[c][s * 4 + 1]);
        o.z = f2bfbits(tile[c][s * 4 + 2]);
        o.w = f2bfbits(tile[c][s * 4 + 3]);
        *reinterpret_cast<ushort4*>(dst + (size_t)(c0 + c) * SB) = o;
    }
}

// P0: p-major param table: pairT[p*OW + o] = {sel[o][p]*8 (LDS byte offset),
// f32 bits of sigmoid(w[o][p])}. Read in K2 as coalesced 512B wave-loads.
__global__ __launch_bounds__(256) void k_prep_params(
        const int* __restrict__ sel, const float* __restrict__ wts,
        int2* __restrict__ pairT) {
    const int tid = blockIdx.x * 256 + threadIdx.x;   // 0 .. OW*PC-1
    const int o = tid & (OW - 1);
    const int p = tid >> 12;
    const int gi = o * PC + p;
    int2 e;
    e.x = sel[gi] * (SB * 2);               // byte offset of row in 32KB slice
    e.y = __float_as_int(sigmoidf_(wts[gi]));
    pairT[(size_t)p * OW + o] = e;
}

// K2 (LDS gather v3): grid 1024 = NSLICE(256) x OQ(4); 512 threads, 32KB LDS
// -> up to 4 blocks/CU (32 waves/CU). ds_read_b64 row gather: 8B rows map to
// 16 bank-groups (vs 8 for b128 rows) -> conflict factor ~2.2 vs ~4.
// Params prefetched 1 iteration ahead (p-major, coalesced); lane owns
// 2 outputs x 4 batches; direct coalesced f32 stores, no shuffles.
__global__ __launch_bounds__(512, 4) void k_gather_lds2(
        const unsigned short* __restrict__ xS,
        const int2* __restrict__ pairT,
        const float* __restrict__ biases,
        float* __restrict__ out) {
    __shared__ unsigned short lds[IW * SB];           // 32 KB
    const int bid   = blockIdx.x;
    const int slice = bid >> 2;                       // 0..255
    const int oq    = bid & 3;                        // output quarter
    const int t     = threadIdx.x;
    // stage slice: 4 rounds x 512 threads x 16B = 32 KB, coalesced
    {
        const uint4* src = reinterpret_cast<const uint4*>(xS + (size_t)slice * IW * SB);
        uint4* dst = reinterpret_cast<uint4*>(lds);
        #pragma unroll
        for (int it = 0; it < 4; ++it)
            dst[t + 512 * it] = src[t + 512 * it];
    }
    __syncthreads();
    const int wv   = t >> 6;                          // 0..7
    const int lane = t & 63;
    const int o0   = oq * 1024 + wv * 128 + lane;
    const int o1   = o0 + 64;
    float a0[4] = {};
    float a1[4] = {};
    int2 c0 = pairT[o0];                              // p = 0
    int2 c1 = pairT[o1];
    #pragma unroll 4
    for (int p = 0; p < PC; ++p) {
        const int pn = (p + 1 < PC) ? (p + 1) : (PC - 1);
        const int2 n0 = pairT[(size_t)pn * OW + o0];  // prefetch next params
        const int2 n1 = pairT[(size_t)pn * OW + o1];
        const uint2 r0 = *reinterpret_cast<const uint2*>((const char*)lds + c0.x);
        const uint2 r1 = *reinterpret_cast<const uint2*>((const char*)lds + c1.x);
        const float w0 = __int_as_float(c0.y);
        const float w1 = __int_as_float(c1.y);
        a0[0] = fmaf(w0, __uint_as_float(r0.x << 16),         a0[0]);
        a0[1] = fmaf(w0, __uint_as_float(r0.x & 0xffff0000u), a0[1]);
        a0[2] = fmaf(w0, __uint_as_float(r0.y << 16),         a0[2]);
        a0[3] = fmaf(w0, __uint_as_float(r0.y & 0xffff0000u), a0[3]);
        a1[0] = fmaf(w1, __uint_as_float(r1.x << 16),         a1[0]);
        a1[1] = fmaf(w1, __uint_as_float(r1.x & 0xffff0000u), a1[1]);
        a1[2] = fmaf(w1, __uint_as_float(r1.y << 16),         a1[2]);
        a1[3] = fmaf(w1, __uint_as_float(r1.y & 0xffff0000u), a1[3]);
        c0 = n0;
        c1 = n1;
    }
    const float b0v = biases[o0];
    const float b1v = biases[o1];
    // r.x lo = batch 0, hi = batch 1; r.y lo = batch 2, hi = batch 3
    #pragma unroll
    for (int b = 0; b < 4; ++b) {
        out[(size_t)(slice * SB + b) * OW + o0] = sigmoidf_(a0[b] - b0v);
        out[(size_t)(slice * SB + b) * OW + o1] = sigmoidf_(a1[b] - b1v);
    }
}

// Fallback (correctness-only) if ws is too small for staging.
__global__ __launch_bounds__(256) void k_naive(
        const float* __restrict__ x, const int* __restrict__ sel,
        const float* __restrict__ w, const float* __restrict__ biases,
        float* __restrict__ out) {
    __shared__ int   s_idx[PC];
    __shared__ float s_wa[PC];
    const int o = blockIdx.x;
    const int t = threadIdx.x;
    if (t < PC) {
        s_idx[t] = sel[o * PC + t];
        s_wa[t]  = sigmoidf_(w[o * PC + t]);
    }
    __syncthreads();
    const int b4 = t * 4;
    float a[4] = {0.f, 0.f, 0.f, 0.f};
    for (int p = 0; p < PC; ++p) {
        const int   idx = s_idx[p];
        const float wa  = s_wa[p];
        #pragma unroll
        for (int k = 0; k < 4; ++k)
            a[k] = fmaf(wa, x[(size_t)(b4 + k) * IW + idx], a[k]);
    }
    const float bo = biases[o];
    #pragma unroll
    for (int k = 0; k < 4; ++k)
        out[(size_t)(b4 + k) * OW + o] = sigmoidf_(a[k] - bo);
}

extern "C" void kernel_launch(void* const* d_in, const int* in_sizes, int n_in,
                              void* d_out, int out_size, void* d_ws, size_t ws_size,
                              hipStream_t stream) {
    const float* x      = (const float*)d_in[0];
    const int*   sel    = (const int*)d_in[1];
    const float* w      = (const float*)d_in[2];
    const float* biases = (const float*)d_in[3];
    float*       out    = (float*)d_out;

    const size_t xS_bytes = (size_t)IW * BATCH * 2;            // 8 MB
    const size_t pt_bytes = (size_t)OW * PC * sizeof(int2);    // 2 MB

    if (ws_size >= xS_bytes + pt_bytes) {
        unsigned short* xS = (unsigned short*)d_ws;
        int2*           pT = (int2*)((char*)d_ws + xS_bytes);
        k_transpose_cast<<<dim3(IW / 64, BATCH / 64), 256, 0, stream>>>(x, xS);
        k_prep_params<<<dim3(OW * PC / 256), 256, 0, stream>>>(sel, w, pT);
        k_gather_lds2<<<dim3(NSLICE * OQ), 512, 0, stream>>>(xS, pT, biases, out);
    } else {
        k_naive<<<OW, 256, 0, stream>>>(x, sel, w, biases, out);
    }
}